// Round 19
// baseline (84.344 us; speedup 1.0000x reference)
//
#include <hip/hip_runtime.h>
#include <hip/hip_bf16.h>
#include <math.h>

#define DD 128
#define SS 1024
#define NROWS 8192
#define EPSF 1e-7f
#define LN_EPSF 1e-3f
#define TCUT 30.0f

typedef __attribute__((ext_vector_type(8))) short bf16x8;
typedef __attribute__((ext_vector_type(8))) _Float16 f16x8;
typedef __attribute__((ext_vector_type(4))) float f32x4;
typedef __attribute__((ext_vector_type(16))) float f32x16;

__device__ __forceinline__ void gload_lds16(const void* g, void* l) {
    __builtin_amdgcn_global_load_lds(
        (const __attribute__((address_space(1))) unsigned int*)g,
        (__attribute__((address_space(3))) unsigned int*)l, 16, 0, 0);
}
__device__ __forceinline__ short f2bf(float v) {
    union { __hip_bfloat16 h; short s; } u;
    u.h = __float2bfloat16(v);
    return u.s;
}
__device__ __forceinline__ float bf2f(short s) {
    union { __hip_bfloat16 h; short s; } u; u.s = s;
    return __bfloat162float(u.h);
}
__device__ __forceinline__ short f2h(float v) {
    union { _Float16 h; short s; } u;
    u.h = (_Float16)v;
    return u.s;
}
__device__ __forceinline__ unsigned int pkmul_f16(unsigned int a, unsigned int b) {
    unsigned int r;
    asm("v_pk_mul_f16 %0, %1, %2" : "=v"(r) : "v"(a), "v"(b));
    return r;
}
__device__ __forceinline__ unsigned int f2h_dup(float v) {
    union { _Float16 h[2]; unsigned int u; } c;
    c.h[0] = (_Float16)v; c.h[1] = c.h[0];
    return c.u;
}

// ---- K0a: emb -> f16 B-fragment layout for k3 (grid 128 j x 4 dt) ----------
__global__ __launch_bounds__(256) void k0a_emb(const float* __restrict__ emb,
                                               short* __restrict__ embB) {
    __shared__ float lt[32][132];
    int j = blockIdx.x, dt = blockIdx.y, t = threadIdx.x;
    {
        int dl = t >> 3, k0 = (t & 7) * 16;
        const float* src = emb + (size_t)(dt * 32 + dl) * 16384 + (size_t)j * 128 + k0;
#pragma unroll
        for (int q = 0; q < 4; ++q)
            *(float4*)&lt[dl][k0 + q * 4] = *(const float4*)(src + q * 4);
    }
    __syncthreads();
    int s = t >> 5, l0 = (t & 31) * 2;
    union { bf16x8 v[2]; short sa[16]; } ob;
#pragma unroll
    for (int li = 0; li < 2; ++li) {
        int l = l0 + li;
        const float* p = &lt[l & 31][s * 16 + (l >> 5) * 8];
#pragma unroll
        for (int e = 0; e < 8; ++e) ob.sa[li * 8 + e] = f2h(p[e]);
    }
    short* dst = embB + (size_t)j * 16384 + dt * 4096 + s * 512 + (size_t)l0 * 8;
    *(bf16x8*)dst = ob.v[0];
    *(bf16x8*)(dst + 8) = ob.v[1];
}

// ---- K0w: split Wq|Wm into bf16 hi/lo fragment-linear for k1 --------------
__global__ __launch_bounds__(256) void k0w_split(const float* __restrict__ Wq,
        const float* __restrict__ Wm, short* __restrict__ Wfrag) {
    int T = blockIdx.x * 256 + threadIdx.x;       // 65536 total
    int e = T & 7, l = (T >> 3) & 63, ks = (T >> 9) & 3, nt = (T >> 11) & 7,
        mat = (T >> 14) & 1;
    int k = ks * 32 + ((l >> 4) & 3) * 8 + e;
    int c = nt * 16 + (l & 15);
    float v = (mat ? Wm : Wq)[k * 128 + c];
    short h = f2bf(v);
    float lo = v - bf2f(h);
    Wfrag[((((size_t)(mat * 2 + 0) * 8 + nt) * 4 + ks) * 64 + l) * 8 + e] = h;
    Wfrag[((((size_t)(mat * 2 + 1) * 8 + nt) * 4 + ks) * 64 + l) * 8 + e] = f2bf(lo);
}

// ---- K1 (fused with k0c): q'/m via split-bf16 MFMA + w,c scalars -----------
__global__ __launch_bounds__(256) void k1_mfma(
    const float* __restrict__ x, const short* __restrict__ Wfrag,
    const float* __restrict__ bq, const float* __restrict__ bm,
    const float* __restrict__ Ww, const float* __restrict__ bw,
    const float* __restrict__ Wc, const float* __restrict__ bc,
    float* __restrict__ mq, float* __restrict__ mo, float* __restrict__ scal)
{
    __shared__ __align__(16) short wl[65536];   // 128 KB
    __shared__ float xs[32][129];               // 16.1 KB
    __shared__ float red[32][4][2];
    int t = threadIdx.x, w = t >> 6, l = t & 63;
    int l15 = l & 15, g = l >> 4;
    int row0 = blockIdx.x * 32;
#pragma unroll
    for (int it = 0; it < 32; ++it)
        gload_lds16(Wfrag + (size_t)(it * 256 + t) * 8, wl + (size_t)(it * 256 + w * 64) * 8);
    {
        int r = t >> 3, d0 = (t & 7) * 16;
        const float4* src = (const float4*)(x + (size_t)(row0 + r) * 128 + d0);
#pragma unroll
        for (int q = 0; q < 4; ++q) *(float4*)&xs[r][d0 + q * 4] = src[q];
    }
    __syncthreads();

    bf16x8 Ah[2][4], Al[2][4];
#pragma unroll
    for (int rf = 0; rf < 2; ++rf)
#pragma unroll
        for (int ks = 0; ks < 4; ++ks) {
            union { bf16x8 v; short sa[8]; } ah, al;
#pragma unroll
            for (int e = 0; e < 8; ++e) {
                float v = xs[rf * 16 + l15][ks * 32 + g * 8 + e];
                short h = f2bf(v);
                ah.sa[e] = h;
                al.sa[e] = f2bf(v - bf2f(h));
            }
            Ah[rf][ks] = ah.v;
            Al[rf][ks] = al.v;
        }

    {
        int rr = t >> 3, seg = t & 7;
        float pw = 0.f, pc = 0.f;
#pragma unroll
        for (int dq = 0; dq < 16; ++dq) {
            float xv = xs[rr][seg * 16 + dq];
            pw = fmaf(xv, Ww[seg * 16 + dq], pw);
            pc = fmaf(xv, Wc[seg * 16 + dq], pc);
        }
        pw += __shfl_xor(pw, 1); pw += __shfl_xor(pw, 2); pw += __shfl_xor(pw, 4);
        pc += __shfl_xor(pc, 1); pc += __shfl_xor(pc, 2); pc += __shfl_xor(pc, 4);
        if (seg == 0) {
            scal[(size_t)(row0 + rr) * 4 + 0] = fmaxf(pw + bw[0], 0.f);
            scal[(size_t)(row0 + rr) * 4 + 1] = fmaxf(pc + bc[0], 0.f);
        }
    }

    f32x4 accq[2][2] = {}, accm[2][2] = {};
#pragma unroll
    for (int ntp = 0; ntp < 2; ++ntp) {
        int nt = w * 2 + ntp;
#pragma unroll
        for (int ks = 0; ks < 4; ++ks) {
            bf16x8 bhq = *(const bf16x8*)(wl + ((size_t)(0  + nt) * 4 + ks) * 512 + l * 8);
            bf16x8 blq = *(const bf16x8*)(wl + ((size_t)(8  + nt) * 4 + ks) * 512 + l * 8);
            bf16x8 bhm = *(const bf16x8*)(wl + ((size_t)(16 + nt) * 4 + ks) * 512 + l * 8);
            bf16x8 blm = *(const bf16x8*)(wl + ((size_t)(24 + nt) * 4 + ks) * 512 + l * 8);
#pragma unroll
            for (int rf = 0; rf < 2; ++rf) {
                accq[rf][ntp] = __builtin_amdgcn_mfma_f32_16x16x32_bf16(Ah[rf][ks], bhq, accq[rf][ntp], 0, 0, 0);
                accq[rf][ntp] = __builtin_amdgcn_mfma_f32_16x16x32_bf16(Ah[rf][ks], blq, accq[rf][ntp], 0, 0, 0);
                accq[rf][ntp] = __builtin_amdgcn_mfma_f32_16x16x32_bf16(Al[rf][ks], bhq, accq[rf][ntp], 0, 0, 0);
                accm[rf][ntp] = __builtin_amdgcn_mfma_f32_16x16x32_bf16(Ah[rf][ks], bhm, accm[rf][ntp], 0, 0, 0);
                accm[rf][ntp] = __builtin_amdgcn_mfma_f32_16x16x32_bf16(Ah[rf][ks], blm, accm[rf][ntp], 0, 0, 0);
                accm[rf][ntp] = __builtin_amdgcn_mfma_f32_16x16x32_bf16(Al[rf][ks], bhm, accm[rf][ntp], 0, 0, 0);
            }
        }
    }
    float sq1[2][4] = {{0,0,0,0},{0,0,0,0}};
    float sq2[2][4] = {{0,0,0,0},{0,0,0,0}};
#pragma unroll
    for (int ntp = 0; ntp < 2; ++ntp) {
        int c = (w * 2 + ntp) * 16 + l15;
        float bqv = bq[c] + EPSF, bmv = bm[c];
#pragma unroll
        for (int rf = 0; rf < 2; ++rf)
#pragma unroll
            for (int reg = 0; reg < 4; ++reg) {
                int rloc = rf * 16 + g * 4 + reg;
                float qp = accq[rf][ntp][reg] + bqv;
                float mv = 1.0f / (1.0f + expf(-(accm[rf][ntp][reg] + bmv)));
                size_t o = (size_t)(row0 + rloc) * 128 + c;
                mq[o] = mv * qp;
                mo[o] = mv;
                sq1[rf][reg] += qp;
                sq2[rf][reg] += qp * qp;
            }
    }
#pragma unroll
    for (int rf = 0; rf < 2; ++rf)
#pragma unroll
        for (int reg = 0; reg < 4; ++reg) {
            float a = sq1[rf][reg], b = sq2[rf][reg];
            a += __shfl_xor(a, 1); a += __shfl_xor(a, 2);
            a += __shfl_xor(a, 4); a += __shfl_xor(a, 8);
            b += __shfl_xor(b, 1); b += __shfl_xor(b, 2);
            b += __shfl_xor(b, 4); b += __shfl_xor(b, 8);
            if (l15 == 0) {
                red[rf * 16 + g * 4 + reg][w][0] = a;
                red[rf * 16 + g * 4 + reg][w][1] = b;
            }
        }
    __syncthreads();
    if (t < 32) {
        float a = red[t][0][0] + red[t][1][0] + red[t][2][0] + red[t][3][0];
        float b = red[t][0][1] + red[t][1][1] + red[t][2][1] + red[t][3][1];
        scal[(size_t)(row0 + t) * 4 + 2] = a;
        scal[(size_t)(row0 + t) * 4 + 3] = sqrtf(b);
    }
}

// ---- K2: windowed pair loop -> qrh2 (f16). One row/block -------------------
__global__ __launch_bounds__(256) void k2_qr(
    const float* __restrict__ x,
    const float* __restrict__ mq, const float* __restrict__ mo,
    const float* __restrict__ scal, short* __restrict__ qrh2)
{
    int row = blockIdx.x;
    int i = row & (SS - 1);
    const float* xb = x + (size_t)(row - i) * DD;
    int t = threadIdx.x, w = t >> 6, l = t & 63;
    int sub = l >> 4, q = l & 15;
    int qo = q * 8;

    float mqv[8], mov[8];
    {
        const float* mp = mq + (size_t)row * DD + qo;
        float4 a = *(const float4*)mp, b = *(const float4*)(mp + 4);
        mqv[0] = a.x; mqv[1] = a.y; mqv[2] = a.z; mqv[3] = a.w;
        mqv[4] = b.x; mqv[5] = b.y; mqv[6] = b.z; mqv[7] = b.w;
        const float* op = mo + (size_t)row * DD + qo;
        float4 c = *(const float4*)op, d = *(const float4*)(op + 4);
        mov[0] = c.x; mov[1] = c.y; mov[2] = c.z; mov[3] = c.w;
        mov[4] = d.x; mov[5] = d.y; mov[6] = d.z; mov[7] = d.w;
    }
    float wv = scal[row * 4 + 0], cv = scal[row * 4 + 1];
    float sumqp = scal[row * 4 + 2], nb = scal[row * 4 + 3];
    float wi = wv + EPSF;
    float dmaxf = cv + TCUT * wi;
    int dmax = (dmaxf >= (float)i) ? i : (int)dmaxf;

    float acc[8] = {0.f, 0.f, 0.f, 0.f, 0.f, 0.f, 0.f, 0.f};
    int nit = (dmax + 15) >> 4;
    int dbase = 1 + w * 4 + sub;
    for (int it = 0; it < nit; ++it) {
        int dist = dbase + it * 16;
        float xv[8];
        if (dist <= dmax) {
            const float* xp = xb + (size_t)(i - dist) * DD + qo;
            float4 a = *(const float4*)xp, b = *(const float4*)(xp + 4);
            xv[0] = a.x; xv[1] = a.y; xv[2] = a.z; xv[3] = a.w;
            xv[4] = b.x; xv[5] = b.y; xv[6] = b.z; xv[7] = b.w;
        } else {
#pragma unroll
            for (int e = 0; e < 8; ++e) xv[e] = 0.f;
        }
        float t1 = 0.f, s1 = 0.f, s2 = 0.f;
#pragma unroll
        for (int e = 0; e < 8; ++e) {
            float xm = xv[e] * mov[e];
            t1 = fmaf(xv[e], mqv[e], t1);
            s1 += xm;
            s2 = fmaf(xm, xm, s2);
        }
#pragma unroll
        for (int off = 1; off < 16; off <<= 1) {
            t1 += __shfl_xor(t1, off);
            s1 += __shfl_xor(s1, off);
            s2 += __shfl_xor(s2, off);
        }
        float tt = ((float)dist - cv) / wi;
        float pe = 1.0f / coshf(tt);
        float dotv = fmaf(pe, t1, EPSF * sumqp);
        float na = sqrtf(fmaf(pe * pe, s2,
                         fmaf(2.0f * EPSF * pe, s1, (float)DD * EPSF * EPSF)));
        float cosv = fminf(1.0f, fmaxf(-1.0f, dotv / (na * nb)));
        float ang = acosf(cosv);
        float wgt = pe * ang;
#pragma unroll
        for (int e = 0; e < 8; ++e) acc[e] = fmaf(wgt, xv[e], acc[e]);
    }
#pragma unroll
    for (int e = 0; e < 8; ++e) {
        acc[e] += __shfl_xor(acc[e], 16);
        acc[e] += __shfl_xor(acc[e], 32);
    }
    __shared__ float sq[4][DD];
    if (l < 16) {
#pragma unroll
        for (int e = 0; e < 8; ++e) sq[w][qo + e] = acc[e];
    }
    __syncthreads();
    if (t < DD) {
        float v = sq[0][t] + sq[1][t] + sq[2][t] + sq[3][t];
        int rbq = row >> 7, rr = row & 127, rt2 = rr >> 5, lp = rr & 31;
        int k = t;
        qrh2[(((size_t)(rbq * 4 + rt2) * 8 + (k >> 4)) * 64
              + (lp + 32 * ((k >> 3) & 1))) * 8 + (k & 7)] = f2h(v);
    }
}

// ---- K3: GEMM over K=(j,k), r18 pipeline at 8 waves (4 waves/SIMD) ---------
// ONLY change vs r18: 512 thr, 8 waves = (rh 4 x dh 2); wave owns 32 rows
// (rt=1) x 64 d. ~105 live VGPR -> launch_bounds(512,4) = 4 waves/SIMD
// (every prior ~43us k3 ran 2/SIMD -- the one untested clean lever).
// Same counted-wait ping-pong (loads in flight across the barrier).
__global__ __launch_bounds__(512, 4) void k3_gemm(
    const float* __restrict__ x, const short* __restrict__ embB,
    const short* __restrict__ qrh2, short* __restrict__ partb)
{
    __shared__ __align__(16) short bB[2][16384];   // 64 KB ping-pong / sof alias
    __shared__ unsigned int xtd[16][132];          // 8.4 KB dup-f16 x
    int t = threadIdx.x, w = t >> 6, l = t & 63;
    int l31 = l & 31, hi = l >> 5;
    int rh = w >> 1, dh = w & 1;
    int rb = blockIdx.x, js = blockIdx.y;

    {
        int r = t >> 2, jq = (t & 3) * 4;
        const float* xp = x + (size_t)(rb * 128 + r) * 128 + js * 16 + jq;
        float4 a = *(const float4*)xp;
        xtd[jq + 0][r] = f2h_dup(a.x); xtd[jq + 1][r] = f2h_dup(a.y);
        xtd[jq + 2][r] = f2h_dup(a.z); xtd[jq + 3][r] = f2h_dup(a.w);
    }

    {
        const short* src = embB + (size_t)(js * 16) * 16384;
#pragma unroll
        for (int i = 0; i < 4; ++i)
            gload_lds16(src + (size_t)(i * 512 + t) * 8,
                        &bB[0][0] + (size_t)(i * 512 + w * 64) * 8);
    }

    unsigned int qrp[8][4];
    {
        int R32 = rb * 4 + rh;
#pragma unroll
        for (int s = 0; s < 8; ++s) {
            union { f16x8 v; unsigned int u[4]; } qb;
            qb.v = *(const f16x8*)(qrh2 + (((size_t)R32 * 8 + s) * 64 + l) * 8);
#pragma unroll
            for (int p = 0; p < 4; ++p) qrp[s][p] = qb.u[p];
        }
    }

    f32x16 acc[2];
#pragma unroll
    for (int i = 0; i < 2; ++i)
#pragma unroll
        for (int q = 0; q < 16; ++q) acc[i][q] = 0.f;

#pragma unroll 1
    for (int jj = 0; jj < 16; ++jj) {
        int cur = jj & 1;
        asm volatile("s_waitcnt vmcnt(0) lgkmcnt(0)" ::: "memory");
        __builtin_amdgcn_s_barrier();
        __builtin_amdgcn_sched_barrier(0);
        if (jj < 15) {
            const short* src = embB + (size_t)(js * 16 + jj + 1) * 16384;
#pragma unroll
            for (int i = 0; i < 4; ++i)
                gload_lds16(src + (size_t)(i * 512 + t) * 8,
                            &bB[cur ^ 1][0] + (size_t)(i * 512 + w * 64) * 8);
        }
        unsigned int xs0 = xtd[jj][rh * 32 + l31];
        const short* bb = &bB[cur][0] + (size_t)(dh * 2) * 4096 + (size_t)l * 8;
#pragma unroll
        for (int s = 0; s < 8; ++s) {
            f16x8 Bd0 = *(const f16x8*)(bb + s * 512);
            f16x8 Bd1 = *(const f16x8*)(bb + 4096 + s * 512);
            union { f16x8 v; unsigned int u[4]; } a0;
#pragma unroll
            for (int p = 0; p < 4; ++p) a0.u[p] = pkmul_f16(qrp[s][p], xs0);
            acc[0] = __builtin_amdgcn_mfma_f32_32x32x16_f16(a0.v, Bd0, acc[0], 0, 0, 0);
            acc[1] = __builtin_amdgcn_mfma_f32_32x32x16_f16(a0.v, Bd1, acc[1], 0, 0, 0);
        }
    }

    __syncthreads();   // full drain once before aliasing bB as sof
    short* sofh = &bB[0][0];   // [128][136] bf16 = 34 KB
#pragma unroll
    for (int i = 0; i < 2; ++i)
#pragma unroll
        for (int q = 0; q < 16; ++q) {
            int r = rh * 32 + (q & 3) + 8 * (q >> 2) + 4 * hi;
            int c = dh * 64 + i * 32 + l31;
            sofh[r * 136 + c] = f2bf(acc[i][q]);
        }
    __syncthreads();
    size_t pbase = (size_t)js * ((size_t)NROWS * DD);
#pragma unroll
    for (int i = 0; i < 4; ++i) {
        int idx = i * 512 + t;
        int r = idx >> 4, c8 = (idx & 15) * 8;
        *(bf16x8*)(partb + pbase + (size_t)(rb * 128 + r) * 128 + c8)
            = *(const bf16x8*)(sofh + r * 136 + c8);
    }
}

// ---- K4: sum 8 bf16 partials + x, LayerNorm (vectorized) -------------------
__global__ __launch_bounds__(256) void k4_ln(
    const float* __restrict__ x, const short* __restrict__ partb,
    const float* __restrict__ gamma, const float* __restrict__ beta,
    float* __restrict__ out)
{
    int t = threadIdx.x;
    int rl = t >> 5, lane32 = t & 31;
    int row = blockIdx.x * 8 + rl;
    int c4 = lane32 * 4;
    size_t base = (size_t)row * DD + c4;
    float4 r = *(const float4*)(x + base);
#pragma unroll
    for (int p = 0; p < 8; ++p) {
        ushort4 u = *(const ushort4*)((const unsigned short*)partb
                                      + (size_t)p * 1048576 + base);
        r.x += bf2f((short)u.x); r.y += bf2f((short)u.y);
        r.z += bf2f((short)u.z); r.w += bf2f((short)u.w);
    }
    float s = r.x + r.y + r.z + r.w;
    float s2 = r.x * r.x + r.y * r.y + r.z * r.z + r.w * r.w;
#pragma unroll
    for (int off = 1; off < 32; off <<= 1) {
        s += __shfl_xor(s, off);
        s2 += __shfl_xor(s2, off);
    }
    float mu = s * (1.0f / DD);
    float var = s2 * (1.0f / DD) - mu * mu;
    var = fmaxf(var, 0.0f);
    float rs = rsqrtf(var + LN_EPSF);
    float4 g = *(const float4*)(gamma + c4);
    float4 b = *(const float4*)(beta + c4);
    float4 o;
    o.x = (r.x - mu) * rs * g.x + b.x;
    o.y = (r.y - mu) * rs * g.y + b.y;
    o.z = (r.z - mu) * rs * g.z + b.z;
    o.w = (r.w - mu) * rs * g.w + b.w;
    *(float4*)(out + base) = o;
}

extern "C" void kernel_launch(void* const* d_in, const int* in_sizes, int n_in,
                              void* d_out, int out_size, void* d_ws, size_t ws_size,
                              hipStream_t stream) {
    const float* x     = (const float*)d_in[0];
    const float* Wq    = (const float*)d_in[1];
    const float* bq    = (const float*)d_in[2];
    const float* Wm    = (const float*)d_in[3];
    const float* bm    = (const float*)d_in[4];
    const float* Ww    = (const float*)d_in[5];
    const float* bw    = (const float*)d_in[6];
    const float* Wc    = (const float*)d_in[7];
    const float* bc    = (const float*)d_in[8];
    const float* emb   = (const float*)d_in[9];
    const float* gamma = (const float*)d_in[10];
    const float* beta  = (const float*)d_in[11];
    float* out = (float*)d_out;
    float* ws  = (float*)d_ws;

    short* embB  = (short*)ws;                  // 4 MB (f16)
    short* qrh2  = (short*)(ws + 1048576);      // 2 MB (f16)
    float* scal  = ws + 1572864;
    short* partb = (short*)(ws + 1605632);      // 16 MB (8 bf16 planes)
    float* tr    = ws + 1605632;                // transients alias partb
    float* mq    = tr + 1048576;
    float* mo    = tr + 2097152;
    short* Wfrag = (short*)(tr + 3145728);

    hipLaunchKernelGGL(k0a_emb,   dim3(128, 4), dim3(256), 0, stream, emb, embB);
    hipLaunchKernelGGL(k0w_split, dim3(256),    dim3(256), 0, stream, Wq, Wm, Wfrag);
    hipLaunchKernelGGL(k1_mfma,   dim3(256),    dim3(256), 0, stream,
                       x, Wfrag, bq, bm, Ww, bw, Wc, bc, mq, mo, scal);
    hipLaunchKernelGGL(k2_qr,     dim3(8192),   dim3(256), 0, stream,
                       x, mq, mo, scal, qrh2);
    hipLaunchKernelGGL(k3_gemm,   dim3(64, 8),  dim3(512), 0, stream,
                       x, embB, qrh2, partb);
    hipLaunchKernelGGL(k4_ln,     dim3(1024),   dim3(256), 0, stream,
                       x, partb, gamma, beta, out);
}

// Round 20
// 82.785 us; speedup vs baseline: 1.0188x; 1.0188x over previous
//
#include <hip/hip_runtime.h>
#include <hip/hip_bf16.h>
#include <math.h>

#define DD 128
#define SS 1024
#define NROWS 8192
#define EPSF 1e-7f
#define LN_EPSF 1e-3f
#define TCUT 30.0f

typedef __attribute__((ext_vector_type(8))) short bf16x8;
typedef __attribute__((ext_vector_type(8))) _Float16 f16x8;
typedef __attribute__((ext_vector_type(4))) float f32x4;
typedef __attribute__((ext_vector_type(16))) float f32x16;

__device__ __forceinline__ void gload_lds16(const void* g, void* l) {
    __builtin_amdgcn_global_load_lds(
        (const __attribute__((address_space(1))) unsigned int*)g,
        (__attribute__((address_space(3))) unsigned int*)l, 16, 0, 0);
}
__device__ __forceinline__ short f2bf(float v) {
    union { __hip_bfloat16 h; short s; } u;
    u.h = __float2bfloat16(v);
    return u.s;
}
__device__ __forceinline__ float bf2f(short s) {
    union { __hip_bfloat16 h; short s; } u; u.s = s;
    return __bfloat162float(u.h);
}
__device__ __forceinline__ short f2h(float v) {
    union { _Float16 h; short s; } u;
    u.h = (_Float16)v;
    return u.s;
}
__device__ __forceinline__ unsigned int pkmul_f16(unsigned int a, unsigned int b) {
    unsigned int r;
    asm("v_pk_mul_f16 %0, %1, %2" : "=v"(r) : "v"(a), "v"(b));
    return r;
}
__device__ __forceinline__ unsigned int f2h_dup(float v) {
    union { _Float16 h[2]; unsigned int u; } c;
    c.h[0] = (_Float16)v; c.h[1] = c.h[0];
    return c.u;
}

// ---- K0a: emb -> f16 B-fragment layout for k3 (grid 128 j x 4 dt) ----------
__global__ __launch_bounds__(256) void k0a_emb(const float* __restrict__ emb,
                                               short* __restrict__ embB) {
    __shared__ float lt[32][132];
    int j = blockIdx.x, dt = blockIdx.y, t = threadIdx.x;
    {
        int dl = t >> 3, k0 = (t & 7) * 16;
        const float* src = emb + (size_t)(dt * 32 + dl) * 16384 + (size_t)j * 128 + k0;
#pragma unroll
        for (int q = 0; q < 4; ++q)
            *(float4*)&lt[dl][k0 + q * 4] = *(const float4*)(src + q * 4);
    }
    __syncthreads();
    int s = t >> 5, l0 = (t & 31) * 2;
    union { bf16x8 v[2]; short sa[16]; } ob;
#pragma unroll
    for (int li = 0; li < 2; ++li) {
        int l = l0 + li;
        const float* p = &lt[l & 31][s * 16 + (l >> 5) * 8];
#pragma unroll
        for (int e = 0; e < 8; ++e) ob.sa[li * 8 + e] = f2h(p[e]);
    }
    short* dst = embB + (size_t)j * 16384 + dt * 4096 + s * 512 + (size_t)l0 * 8;
    *(bf16x8*)dst = ob.v[0];
    *(bf16x8*)(dst + 8) = ob.v[1];
}

// ---- K0w: split Wq|Wm into bf16 hi/lo fragment-linear for k1 --------------
__global__ __launch_bounds__(256) void k0w_split(const float* __restrict__ Wq,
        const float* __restrict__ Wm, short* __restrict__ Wfrag) {
    int T = blockIdx.x * 256 + threadIdx.x;       // 65536 total
    int e = T & 7, l = (T >> 3) & 63, ks = (T >> 9) & 3, nt = (T >> 11) & 7,
        mat = (T >> 14) & 1;
    int k = ks * 32 + ((l >> 4) & 3) * 8 + e;
    int c = nt * 16 + (l & 15);
    float v = (mat ? Wm : Wq)[k * 128 + c];
    short h = f2bf(v);
    float lo = v - bf2f(h);
    Wfrag[((((size_t)(mat * 2 + 0) * 8 + nt) * 4 + ks) * 64 + l) * 8 + e] = h;
    Wfrag[((((size_t)(mat * 2 + 1) * 8 + nt) * 4 + ks) * 64 + l) * 8 + e] = f2bf(lo);
}

// ---- K1 (fused with k0c): q'/m via split-bf16 MFMA + w,c scalars -----------
__global__ __launch_bounds__(256) void k1_mfma(
    const float* __restrict__ x, const short* __restrict__ Wfrag,
    const float* __restrict__ bq, const float* __restrict__ bm,
    const float* __restrict__ Ww, const float* __restrict__ bw,
    const float* __restrict__ Wc, const float* __restrict__ bc,
    float* __restrict__ mq, float* __restrict__ mo, float* __restrict__ scal)
{
    __shared__ __align__(16) short wl[65536];   // 128 KB
    __shared__ float xs[32][129];               // 16.1 KB
    __shared__ float red[32][4][2];
    int t = threadIdx.x, w = t >> 6, l = t & 63;
    int l15 = l & 15, g = l >> 4;
    int row0 = blockIdx.x * 32;
#pragma unroll
    for (int it = 0; it < 32; ++it)
        gload_lds16(Wfrag + (size_t)(it * 256 + t) * 8, wl + (size_t)(it * 256 + w * 64) * 8);
    {
        int r = t >> 3, d0 = (t & 7) * 16;
        const float4* src = (const float4*)(x + (size_t)(row0 + r) * 128 + d0);
#pragma unroll
        for (int q = 0; q < 4; ++q) *(float4*)&xs[r][d0 + q * 4] = src[q];
    }
    __syncthreads();

    bf16x8 Ah[2][4], Al[2][4];
#pragma unroll
    for (int rf = 0; rf < 2; ++rf)
#pragma unroll
        for (int ks = 0; ks < 4; ++ks) {
            union { bf16x8 v; short sa[8]; } ah, al;
#pragma unroll
            for (int e = 0; e < 8; ++e) {
                float v = xs[rf * 16 + l15][ks * 32 + g * 8 + e];
                short h = f2bf(v);
                ah.sa[e] = h;
                al.sa[e] = f2bf(v - bf2f(h));
            }
            Ah[rf][ks] = ah.v;
            Al[rf][ks] = al.v;
        }

    {
        int rr = t >> 3, seg = t & 7;
        float pw = 0.f, pc = 0.f;
#pragma unroll
        for (int dq = 0; dq < 16; ++dq) {
            float xv = xs[rr][seg * 16 + dq];
            pw = fmaf(xv, Ww[seg * 16 + dq], pw);
            pc = fmaf(xv, Wc[seg * 16 + dq], pc);
        }
        pw += __shfl_xor(pw, 1); pw += __shfl_xor(pw, 2); pw += __shfl_xor(pw, 4);
        pc += __shfl_xor(pc, 1); pc += __shfl_xor(pc, 2); pc += __shfl_xor(pc, 4);
        if (seg == 0) {
            scal[(size_t)(row0 + rr) * 4 + 0] = fmaxf(pw + bw[0], 0.f);
            scal[(size_t)(row0 + rr) * 4 + 1] = fmaxf(pc + bc[0], 0.f);
        }
    }

    f32x4 accq[2][2] = {}, accm[2][2] = {};
#pragma unroll
    for (int ntp = 0; ntp < 2; ++ntp) {
        int nt = w * 2 + ntp;
#pragma unroll
        for (int ks = 0; ks < 4; ++ks) {
            bf16x8 bhq = *(const bf16x8*)(wl + ((size_t)(0  + nt) * 4 + ks) * 512 + l * 8);
            bf16x8 blq = *(const bf16x8*)(wl + ((size_t)(8  + nt) * 4 + ks) * 512 + l * 8);
            bf16x8 bhm = *(const bf16x8*)(wl + ((size_t)(16 + nt) * 4 + ks) * 512 + l * 8);
            bf16x8 blm = *(const bf16x8*)(wl + ((size_t)(24 + nt) * 4 + ks) * 512 + l * 8);
#pragma unroll
            for (int rf = 0; rf < 2; ++rf) {
                accq[rf][ntp] = __builtin_amdgcn_mfma_f32_16x16x32_bf16(Ah[rf][ks], bhq, accq[rf][ntp], 0, 0, 0);
                accq[rf][ntp] = __builtin_amdgcn_mfma_f32_16x16x32_bf16(Ah[rf][ks], blq, accq[rf][ntp], 0, 0, 0);
                accq[rf][ntp] = __builtin_amdgcn_mfma_f32_16x16x32_bf16(Al[rf][ks], bhq, accq[rf][ntp], 0, 0, 0);
                accm[rf][ntp] = __builtin_amdgcn_mfma_f32_16x16x32_bf16(Ah[rf][ks], bhm, accm[rf][ntp], 0, 0, 0);
                accm[rf][ntp] = __builtin_amdgcn_mfma_f32_16x16x32_bf16(Ah[rf][ks], blm, accm[rf][ntp], 0, 0, 0);
                accm[rf][ntp] = __builtin_amdgcn_mfma_f32_16x16x32_bf16(Al[rf][ks], bhm, accm[rf][ntp], 0, 0, 0);
            }
        }
    }
    float sq1[2][4] = {{0,0,0,0},{0,0,0,0}};
    float sq2[2][4] = {{0,0,0,0},{0,0,0,0}};
#pragma unroll
    for (int ntp = 0; ntp < 2; ++ntp) {
        int c = (w * 2 + ntp) * 16 + l15;
        float bqv = bq[c] + EPSF, bmv = bm[c];
#pragma unroll
        for (int rf = 0; rf < 2; ++rf)
#pragma unroll
            for (int reg = 0; reg < 4; ++reg) {
                int rloc = rf * 16 + g * 4 + reg;
                float qp = accq[rf][ntp][reg] + bqv;
                float mv = 1.0f / (1.0f + expf(-(accm[rf][ntp][reg] + bmv)));
                size_t o = (size_t)(row0 + rloc) * 128 + c;
                mq[o] = mv * qp;
                mo[o] = mv;
                sq1[rf][reg] += qp;
                sq2[rf][reg] += qp * qp;
            }
    }
#pragma unroll
    for (int rf = 0; rf < 2; ++rf)
#pragma unroll
        for (int reg = 0; reg < 4; ++reg) {
            float a = sq1[rf][reg], b = sq2[rf][reg];
            a += __shfl_xor(a, 1); a += __shfl_xor(a, 2);
            a += __shfl_xor(a, 4); a += __shfl_xor(a, 8);
            b += __shfl_xor(b, 1); b += __shfl_xor(b, 2);
            b += __shfl_xor(b, 4); b += __shfl_xor(b, 8);
            if (l15 == 0) {
                red[rf * 16 + g * 4 + reg][w][0] = a;
                red[rf * 16 + g * 4 + reg][w][1] = b;
            }
        }
    __syncthreads();
    if (t < 32) {
        float a = red[t][0][0] + red[t][1][0] + red[t][2][0] + red[t][3][0];
        float b = red[t][0][1] + red[t][1][1] + red[t][2][1] + red[t][3][1];
        scal[(size_t)(row0 + t) * 4 + 2] = a;
        scal[(size_t)(row0 + t) * 4 + 3] = sqrtf(b);
    }
}

// ---- K2: windowed pair loop -> qrh2 (f16). One row/block -------------------
__global__ __launch_bounds__(256) void k2_qr(
    const float* __restrict__ x,
    const float* __restrict__ mq, const float* __restrict__ mo,
    const float* __restrict__ scal, short* __restrict__ qrh2)
{
    int row = blockIdx.x;
    int i = row & (SS - 1);
    const float* xb = x + (size_t)(row - i) * DD;
    int t = threadIdx.x, w = t >> 6, l = t & 63;
    int sub = l >> 4, q = l & 15;
    int qo = q * 8;

    float mqv[8], mov[8];
    {
        const float* mp = mq + (size_t)row * DD + qo;
        float4 a = *(const float4*)mp, b = *(const float4*)(mp + 4);
        mqv[0] = a.x; mqv[1] = a.y; mqv[2] = a.z; mqv[3] = a.w;
        mqv[4] = b.x; mqv[5] = b.y; mqv[6] = b.z; mqv[7] = b.w;
        const float* op = mo + (size_t)row * DD + qo;
        float4 c = *(const float4*)op, d = *(const float4*)(op + 4);
        mov[0] = c.x; mov[1] = c.y; mov[2] = c.z; mov[3] = c.w;
        mov[4] = d.x; mov[5] = d.y; mov[6] = d.z; mov[7] = d.w;
    }
    float wv = scal[row * 4 + 0], cv = scal[row * 4 + 1];
    float sumqp = scal[row * 4 + 2], nb = scal[row * 4 + 3];
    float wi = wv + EPSF;
    float dmaxf = cv + TCUT * wi;
    int dmax = (dmaxf >= (float)i) ? i : (int)dmaxf;

    float acc[8] = {0.f, 0.f, 0.f, 0.f, 0.f, 0.f, 0.f, 0.f};
    int nit = (dmax + 15) >> 4;
    int dbase = 1 + w * 4 + sub;
    for (int it = 0; it < nit; ++it) {
        int dist = dbase + it * 16;
        float xv[8];
        if (dist <= dmax) {
            const float* xp = xb + (size_t)(i - dist) * DD + qo;
            float4 a = *(const float4*)xp, b = *(const float4*)(xp + 4);
            xv[0] = a.x; xv[1] = a.y; xv[2] = a.z; xv[3] = a.w;
            xv[4] = b.x; xv[5] = b.y; xv[6] = b.z; xv[7] = b.w;
        } else {
#pragma unroll
            for (int e = 0; e < 8; ++e) xv[e] = 0.f;
        }
        float t1 = 0.f, s1 = 0.f, s2 = 0.f;
#pragma unroll
        for (int e = 0; e < 8; ++e) {
            float xm = xv[e] * mov[e];
            t1 = fmaf(xv[e], mqv[e], t1);
            s1 += xm;
            s2 = fmaf(xm, xm, s2);
        }
#pragma unroll
        for (int off = 1; off < 16; off <<= 1) {
            t1 += __shfl_xor(t1, off);
            s1 += __shfl_xor(s1, off);
            s2 += __shfl_xor(s2, off);
        }
        float tt = ((float)dist - cv) / wi;
        float pe = 1.0f / coshf(tt);
        float dotv = fmaf(pe, t1, EPSF * sumqp);
        float na = sqrtf(fmaf(pe * pe, s2,
                         fmaf(2.0f * EPSF * pe, s1, (float)DD * EPSF * EPSF)));
        float cosv = fminf(1.0f, fmaxf(-1.0f, dotv / (na * nb)));
        float ang = acosf(cosv);
        float wgt = pe * ang;
#pragma unroll
        for (int e = 0; e < 8; ++e) acc[e] = fmaf(wgt, xv[e], acc[e]);
    }
#pragma unroll
    for (int e = 0; e < 8; ++e) {
        acc[e] += __shfl_xor(acc[e], 16);
        acc[e] += __shfl_xor(acc[e], 32);
    }
    __shared__ float sq[4][DD];
    if (l < 16) {
#pragma unroll
        for (int e = 0; e < 8; ++e) sq[w][qo + e] = acc[e];
    }
    __syncthreads();
    if (t < DD) {
        float v = sq[0][t] + sq[1][t] + sq[2][t] + sq[3][t];
        int rbq = row >> 7, rr = row & 127, rt2 = rr >> 5, lp = rr & 31;
        int k = t;
        qrh2[(((size_t)(rbq * 4 + rt2) * 8 + (k >> 4)) * 64
              + (lp + 32 * ((k >> 3) & 1))) * 8 + (k & 7)] = f2h(v);
    }
}

// ---- K3: GEMM over K=(j,k), r18 counted-wait pipeline (best measured) ------
__global__ __launch_bounds__(256, 2) void k3_gemm(
    const float* __restrict__ x, const short* __restrict__ embB,
    const short* __restrict__ qrh2, short* __restrict__ partb)
{
    __shared__ __align__(16) short bB[2][16384];   // 64 KB ping-pong / sof alias
    __shared__ unsigned int xtd[16][132];          // 8.4 KB dup-f16 x
    int t = threadIdx.x, w = t >> 6, l = t & 63;
    int l31 = l & 31, hi = l >> 5;
    int rh = w >> 1, dh = w & 1;
    int rb = blockIdx.x, js = blockIdx.y;

    {
        int r = t >> 1, jq = (t & 1) * 8;
        const float* xp = x + (size_t)(rb * 128 + r) * 128 + js * 16 + jq;
        float4 a = *(const float4*)xp, b = *(const float4*)(xp + 4);
        xtd[jq + 0][r] = f2h_dup(a.x); xtd[jq + 1][r] = f2h_dup(a.y);
        xtd[jq + 2][r] = f2h_dup(a.z); xtd[jq + 3][r] = f2h_dup(a.w);
        xtd[jq + 4][r] = f2h_dup(b.x); xtd[jq + 5][r] = f2h_dup(b.y);
        xtd[jq + 6][r] = f2h_dup(b.z); xtd[jq + 7][r] = f2h_dup(b.w);
    }

    {
        const short* src = embB + (size_t)(js * 16) * 16384;
#pragma unroll
        for (int i = 0; i < 8; ++i)
            gload_lds16(src + (size_t)(i * 256 + t) * 8,
                        &bB[0][0] + (size_t)(i * 256 + w * 64) * 8);
    }

    unsigned int qrp[2][8][4];
#pragma unroll
    for (int rt = 0; rt < 2; ++rt) {
        int R32 = rb * 4 + rh * 2 + rt;
#pragma unroll
        for (int s = 0; s < 8; ++s) {
            union { f16x8 v; unsigned int u[4]; } qb;
            qb.v = *(const f16x8*)(qrh2 + (((size_t)R32 * 8 + s) * 64 + l) * 8);
#pragma unroll
            for (int p = 0; p < 4; ++p) qrp[rt][s][p] = qb.u[p];
        }
    }

    f32x16 acc[2][2];
#pragma unroll
    for (int rt = 0; rt < 2; ++rt)
#pragma unroll
        for (int i = 0; i < 2; ++i)
#pragma unroll
            for (int q = 0; q < 16; ++q) acc[rt][i][q] = 0.f;

#pragma unroll 1
    for (int jj = 0; jj < 16; ++jj) {
        int cur = jj & 1;
        asm volatile("s_waitcnt vmcnt(0) lgkmcnt(0)" ::: "memory");
        __builtin_amdgcn_s_barrier();
        __builtin_amdgcn_sched_barrier(0);
        if (jj < 15) {
            const short* src = embB + (size_t)(js * 16 + jj + 1) * 16384;
#pragma unroll
            for (int i = 0; i < 8; ++i)
                gload_lds16(src + (size_t)(i * 256 + t) * 8,
                            &bB[cur ^ 1][0] + (size_t)(i * 256 + w * 64) * 8);
        }
        unsigned int xs0 = xtd[jj][rh * 64 + l31];
        unsigned int xs1 = xtd[jj][rh * 64 + 32 + l31];
        const short* bb = &bB[cur][0] + (size_t)(dh * 2) * 4096 + (size_t)l * 8;
#pragma unroll
        for (int s = 0; s < 8; ++s) {
            f16x8 Bd0 = *(const f16x8*)(bb + s * 512);
            f16x8 Bd1 = *(const f16x8*)(bb + 4096 + s * 512);
            union { f16x8 v; unsigned int u[4]; } a0, a1;
#pragma unroll
            for (int p = 0; p < 4; ++p) {
                a0.u[p] = pkmul_f16(qrp[0][s][p], xs0);
                a1.u[p] = pkmul_f16(qrp[1][s][p], xs1);
            }
            acc[0][0] = __builtin_amdgcn_mfma_f32_32x32x16_f16(a0.v, Bd0, acc[0][0], 0, 0, 0);
            acc[0][1] = __builtin_amdgcn_mfma_f32_32x32x16_f16(a0.v, Bd1, acc[0][1], 0, 0, 0);
            acc[1][0] = __builtin_amdgcn_mfma_f32_32x32x16_f16(a1.v, Bd0, acc[1][0], 0, 0, 0);
            acc[1][1] = __builtin_amdgcn_mfma_f32_32x32x16_f16(a1.v, Bd1, acc[1][1], 0, 0, 0);
        }
    }

    __syncthreads();   // full drain once before aliasing bB as sof
    short* sofh = &bB[0][0];   // [128][136] bf16 = 34 KB
#pragma unroll
    for (int rt = 0; rt < 2; ++rt)
#pragma unroll
        for (int i = 0; i < 2; ++i)
#pragma unroll
            for (int q = 0; q < 16; ++q) {
                int r = rh * 64 + rt * 32 + (q & 3) + 8 * (q >> 2) + 4 * hi;
                int c = dh * 64 + i * 32 + l31;
                sofh[r * 136 + c] = f2bf(acc[rt][i][q]);
            }
    __syncthreads();
    size_t pbase = (size_t)js * ((size_t)NROWS * DD);
#pragma unroll
    for (int i = 0; i < 8; ++i) {
        int idx = i * 256 + t;
        int r = idx >> 4, c8 = (idx & 15) * 8;
        *(bf16x8*)(partb + pbase + (size_t)(rb * 128 + r) * 128 + c8)
            = *(const bf16x8*)(sofh + r * 136 + c8);
    }
}

// ---- K4: sum 8 bf16 partials + x, LayerNorm (16B partial loads) ------------
__global__ __launch_bounds__(256) void k4_ln(
    const float* __restrict__ x, const short* __restrict__ partb,
    const float* __restrict__ gamma, const float* __restrict__ beta,
    float* __restrict__ out)
{
    int t = threadIdx.x;
    int rl = t >> 4, lane16 = t & 15;
    int row = blockIdx.x * 16 + rl;
    int c8 = lane16 * 8;
    size_t base = (size_t)row * DD + c8;
    float r[8];
    {
        float4 a = *(const float4*)(x + base);
        float4 b = *(const float4*)(x + base + 4);
        r[0] = a.x; r[1] = a.y; r[2] = a.z; r[3] = a.w;
        r[4] = b.x; r[5] = b.y; r[6] = b.z; r[7] = b.w;
    }
#pragma unroll
    for (int p = 0; p < 8; ++p) {
        union { bf16x8 v; short sa[8]; } u;
        u.v = *(const bf16x8*)(partb + (size_t)p * 1048576 + base);
#pragma unroll
        for (int e = 0; e < 8; ++e) r[e] += bf2f(u.sa[e]);
    }
    float s = 0.f, s2 = 0.f;
#pragma unroll
    for (int e = 0; e < 8; ++e) { s += r[e]; s2 = fmaf(r[e], r[e], s2); }
#pragma unroll
    for (int off = 1; off < 16; off <<= 1) {
        s += __shfl_xor(s, off);
        s2 += __shfl_xor(s2, off);
    }
    float mu = s * (1.0f / DD);
    float var = s2 * (1.0f / DD) - mu * mu;
    var = fmaxf(var, 0.0f);
    float rs = rsqrtf(var + LN_EPSF);
    float4 g0 = *(const float4*)(gamma + c8);
    float4 g1 = *(const float4*)(gamma + c8 + 4);
    float4 b0 = *(const float4*)(beta + c8);
    float4 b1 = *(const float4*)(beta + c8 + 4);
    float4 o0, o1;
    o0.x = (r[0] - mu) * rs * g0.x + b0.x;
    o0.y = (r[1] - mu) * rs * g0.y + b0.y;
    o0.z = (r[2] - mu) * rs * g0.z + b0.z;
    o0.w = (r[3] - mu) * rs * g0.w + b0.w;
    o1.x = (r[4] - mu) * rs * g1.x + b1.x;
    o1.y = (r[5] - mu) * rs * g1.y + b1.y;
    o1.z = (r[6] - mu) * rs * g1.z + b1.z;
    o1.w = (r[7] - mu) * rs * g1.w + b1.w;
    *(float4*)(out + base) = o0;
    *(float4*)(out + base + 4) = o1;
}

extern "C" void kernel_launch(void* const* d_in, const int* in_sizes, int n_in,
                              void* d_out, int out_size, void* d_ws, size_t ws_size,
                              hipStream_t stream) {
    const float* x     = (const float*)d_in[0];
    const float* Wq    = (const float*)d_in[1];
    const float* bq    = (const float*)d_in[2];
    const float* Wm    = (const float*)d_in[3];
    const float* bm    = (const float*)d_in[4];
    const float* Ww    = (const float*)d_in[5];
    const float* bw    = (const float*)d_in[6];
    const float* Wc    = (const float*)d_in[7];
    const float* bc    = (const float*)d_in[8];
    const float* emb   = (const float*)d_in[9];
    const float* gamma = (const float*)d_in[10];
    const float* beta  = (const float*)d_in[11];
    float* out = (float*)d_out;
    float* ws  = (float*)d_ws;

    short* embB  = (short*)ws;                  // 4 MB (f16)
    short* qrh2  = (short*)(ws + 1048576);      // 2 MB (f16)
    float* scal  = ws + 1572864;
    short* partb = (short*)(ws + 1605632);      // 16 MB (8 bf16 planes)
    float* tr    = ws + 1605632;                // transients alias partb
    float* mq    = tr + 1048576;
    float* mo    = tr + 2097152;
    short* Wfrag = (short*)(tr + 3145728);

    hipLaunchKernelGGL(k0a_emb,   dim3(128, 4), dim3(256), 0, stream, emb, embB);
    hipLaunchKernelGGL(k0w_split, dim3(256),    dim3(256), 0, stream, Wq, Wm, Wfrag);
    hipLaunchKernelGGL(k1_mfma,   dim3(256),    dim3(256), 0, stream,
                       x, Wfrag, bq, bm, Ww, bw, Wc, bc, mq, mo, scal);
    hipLaunchKernelGGL(k2_qr,     dim3(8192),   dim3(256), 0, stream,
                       x, mq, mo, scal, qrh2);
    hipLaunchKernelGGL(k3_gemm,   dim3(64, 8),  dim3(256), 0, stream,
                       x, embB, qrh2, partb);
    hipLaunchKernelGGL(k4_ln,     dim3(512),    dim3(256), 0, stream,
                       x, partb, gamma, beta, out);
}